// Round 9
// baseline (1974.572 us; speedup 1.0000x reference)
//
#include <hip/hip_runtime.h>

#define N_    16
#define DIN   24
#define DOUT  26
#define CIN   64
#define COUT  128
#define NGRP  8
#define EPS   1e-5f

// ws layout (bytes) -- total 443,392 B (proven OK rounds 5-8):
//   [0, 1024)      : float stats[N_][NGRP][2] (sum, sumsq) -- zeroed each launch
//   [1024, 443392) : fp16 Kf[27][4][4][64][8]  (32x32 MFMA B-fragment order)
#define STATS_OFF 0
#define KF_OFF    1024

typedef _Float16 half8_t  __attribute__((ext_vector_type(8)));
typedef float    f32x16_t __attribute__((ext_vector_type(16)));

// ---- build Kf in 32x32x16 B-fragment order + zero stats ----
// frag (tap, ckg, nf): element j of lane: k(ci) = ckg*16 + (lane>>5)*8 + j,
// n(co) = nf*32 + (lane&31).   t = ((tap*4 + ckg)*4 + nf)*64 + lane.
__global__ __launch_bounds__(256) void convert_k_kernel(
    const float* __restrict__ K, _Float16* __restrict__ Kf, float* __restrict__ stats)
{
    int t = blockIdx.x * 256 + threadIdx.x;
    if (blockIdx.x == 0 && threadIdx.x < N_ * NGRP * 2) stats[threadIdx.x] = 0.0f;
    if (t >= 27 * 4 * 4 * 64) return;
    const int lane = t & 63;
    const int nf   = (t >> 6) & 3;
    const int ckg  = (t >> 8) & 3;
    const int tap  = t >> 10;                        // 0..26 = ad*9+ah*3+aw
    const int ci0  = ckg * 16 + (lane >> 5) * 8;
    const int co   = nf * 32 + (lane & 31);
    half8_t h;
    #pragma unroll
    for (int j = 0; j < 8; ++j)
        h[j] = (_Float16)K[(size_t)(tap * CIN + ci0 + j) * COUT + co];
    *(half8_t*)(Kf + (size_t)t * 8) = h;
}

// ---- conv(gather) + ReLU + group sums, 32x32x16 MFMA ----
// Block = (n, d-pair, h-quad). 4 waves: (wv&1)->d, (wv>>1)->cout-pair.
// Each wave: Mt=4 h-rows x Nf=2 cout-frags -> each B frag feeds 4 MFMA
// (B traffic halved vs round 8). ci-split phases keep LDS at 51.8 KB
// (24 rows x 27 slots x 40-half stride) -> 3 blocks/CU.
__global__ __launch_bounds__(256, 3) void conv_mfma_kernel(
    const float* __restrict__ x, const _Float16* __restrict__ Kf,
    float* __restrict__ y, float* __restrict__ stats)
{
    // rows s = dslice*6 + hs: dd = d0+1-dslice (dslice 0..3), hh = hb+hs-2 (hs 0..5)
    // slots 0..26: w = slot-2; slots 0,1,26 always zero (w<0 or w>=24).
    __shared__ __align__(16) _Float16 xs[24 * 27 * 40];   // 51,840 B
    __shared__ float gsum[NGRP], gsq[NGRP];

    const int bid = blockIdx.x;
    const int n     = bid / 91;
    const int rem   = bid % 91;
    const int d0    = (rem / 7) * 2;
    const int hb    = (rem % 7) * 4;
    const int tid = threadIdx.x;

    if (tid < NGRP) { gsum[tid] = 0.0f; gsq[tid] = 0.0f; }

    const int lane = tid & 63;
    const int wv   = tid >> 6;
    const int dp   = wv & 1;            // which d of the pair
    const int nfp  = wv >> 1;           // cout frags nfp*2, nfp*2+1 (32 couts each)
    const int col  = lane & 31;         // A: m(=w) ; B/C/D: n(cout in frag)
    const int hi   = lane >> 5;         // k-half selector

    int aofs[3];
    #pragma unroll
    for (int aw = 0; aw < 3; ++aw) {
        int sl = col - aw + 2; if (sl > 26) sl = 26;   // slot 26 always zero
        aofs[aw] = sl * 40 + hi * 8;
    }

    f32x16_t acc[4][2];
    #pragma unroll
    for (int mt = 0; mt < 4; ++mt)
        #pragma unroll
        for (int fi = 0; fi < 2; ++fi) acc[mt][fi] = (f32x16_t)(0.0f);

    const _Float16* Kfl = Kf + (size_t)lane * 8;

    for (int ph = 0; ph < 2; ++ph) {
        // ---- stage this phase's 32 ci: 24*27*4 = 2592 16-B chunks ----
        for (int c = tid; c < 2592; c += 256) {
            const int s    = c / 108;        // s = dslice*6 + hs
            const int rr   = c % 108;
            const int slot = rr >> 2;        // 0..26, source w = slot - 2
            const int ch   = rr & 3;
            const int dd = d0 + 1 - s / 6;
            const int hh = hb + (s % 6) - 2;
            const int w  = slot - 2;
            half8_t v = {};
            if (dd >= 0 && dd < DIN && hh >= 0 && hh < DIN && w >= 0 && w < DIN) {
                const float* src = x + ((size_t)(((n * DIN + dd) * DIN + hh) * DIN + w)) * CIN
                                     + ph * 32 + ch * 8;
                const float4 a = *(const float4*)(src);
                const float4 b = *(const float4*)(src + 4);
                v[0] = (_Float16)a.x; v[1] = (_Float16)a.y; v[2] = (_Float16)a.z; v[3] = (_Float16)a.w;
                v[4] = (_Float16)b.x; v[5] = (_Float16)b.y; v[6] = (_Float16)b.z; v[7] = (_Float16)b.w;
            }
            *(half8_t*)(xs + s * 1080 + slot * 40 + ch * 8) = v;
        }
        __syncthreads();

        // ---- 27 taps x 2 k16-steps in this ci-half ----
        for (int ad = 0; ad < 3; ++ad) {
            const int dsl = 1 - dp + ad;                 // 0..3 (this wave's dslice)
            for (int ah = 0; ah < 3; ++ah) {
                const int s0   = (dsl * 6 + 2 - ah) * 1080;   // mt row = s0 + mt*1080
                const int tapb = ad * 9 + ah * 3;
                #pragma unroll
                for (int aw = 0; aw < 3; ++aw) {
                    const _Float16* Bt =
                        Kfl + (size_t)((((tapb + aw) * 4 + ph * 2) * 4) + nfp * 2) * 512;
                    #pragma unroll
                    for (int ck = 0; ck < 2; ++ck) {
                        half8_t b0 = *(const half8_t*)(Bt + ck * 2048);
                        half8_t b1 = *(const half8_t*)(Bt + ck * 2048 + 512);
                        #pragma unroll
                        for (int mt = 0; mt < 4; ++mt) {
                            half8_t a = *(const half8_t*)(xs + s0 + mt * 1080 + aofs[aw] + ck * 16);
                            acc[mt][0] = __builtin_amdgcn_mfma_f32_32x32x16_f16(a, b0, acc[mt][0], 0, 0, 0);
                            acc[mt][1] = __builtin_amdgcn_mfma_f32_32x32x16_f16(a, b1, acc[mt][1], 0, 0, 0);
                        }
                    }
                }
            }
        }
        if (ph == 0) __syncthreads();   // protect LDS before re-staging
    }

    // epilogue. C/D (HW-verified): col(cout)=lane&31, row(w)=(reg&3)+8*(reg>>2)+4*hi
    const int d = d0 + dp;
    #pragma unroll
    for (int mt = 0; mt < 4; ++mt) {
        const int hrow = hb + mt;
        if (hrow >= DOUT) continue;
        const size_t rowbase = (((size_t)(n * DOUT + d)) * DOUT + hrow) * (DOUT * COUT);
        #pragma unroll
        for (int fi = 0; fi < 2; ++fi) {
            const int fr   = nfp * 2 + fi;
            const int cout = fr * 32 + col;
            float ls = 0.f, lsq = 0.f;
            #pragma unroll
            for (int reg = 0; reg < 16; ++reg) {
                const int wout = (reg & 3) + 8 * (reg >> 2) + 4 * hi;
                float v = fmaxf(acc[mt][fi][reg], 0.0f);
                if (wout < DOUT) {
                    y[rowbase + (size_t)wout * COUT + cout] = v;
                    ls += v; lsq += v * v;
                }
            }
            // cohort sharing one GN group: same (col>>4) -> xor {1,2,4,8,32}
            #pragma unroll
            for (int off = 1; off < 16; off <<= 1) {
                ls  += __shfl_xor(ls, off);
                lsq += __shfl_xor(lsq, off);
            }
            ls  += __shfl_xor(ls, 32);
            lsq += __shfl_xor(lsq, 32);
            if (lane == 0 || lane == 16) {
                const int g = fr * 2 + (col >> 4);   // 8 groups of 16 couts
                atomicAdd(&gsum[g], ls);
                atomicAdd(&gsq[g], lsq);
            }
        }
    }
    __syncthreads();
    if (tid < NGRP) {
        atomicAdd(&stats[(n * NGRP + tid) * 2 + 0], gsum[tid]);
        atomicAdd(&stats[(n * NGRP + tid) * 2 + 1], gsq[tid]);
    }
}

// ---- elementwise normalize ----
__global__ __launch_bounds__(256) void gn_apply_kernel(
    float* __restrict__ y, const float* __restrict__ stats,
    const float* __restrict__ scale, const float* __restrict__ bias)
{
    const int total4 = N_ * DOUT * DOUT * DOUT * (COUT / 4);
    int i = blockIdx.x * 256 + threadIdx.x;
    if (i >= total4) return;

    const int t  = i & 31;
    const int co = t * 4;
    const int g  = t >> 2;
    const int n  = i / (DOUT * DOUT * DOUT * (COUT / 4));

    const float s  = stats[(n * NGRP + g) * 2 + 0];
    const float sq = stats[(n * NGRP + g) * 2 + 1];
    const float invN = 1.0f / (float)(DOUT * DOUT * DOUT * (COUT / NGRP));
    const float mean = s * invN;
    const float var  = sq * invN - mean * mean;
    const float rstd = rsqrtf(var + EPS);

    float4 v = ((float4*)y)[i];
    const float4 sc = *(const float4*)(scale + co);
    const float4 bi = *(const float4*)(bias + co);
    v.x = (v.x - mean) * rstd * sc.x + bi.x;
    v.y = (v.y - mean) * rstd * sc.y + bi.y;
    v.z = (v.z - mean) * rstd * sc.z + bi.z;
    v.w = (v.w - mean) * rstd * sc.w + bi.w;
    ((float4*)y)[i] = v;
}

extern "C" void kernel_launch(void* const* d_in, const int* in_sizes, int n_in,
                              void* d_out, int out_size, void* d_ws, size_t ws_size,
                              hipStream_t stream) {
    const float* x     = (const float*)d_in[0];
    const float* K     = (const float*)d_in[1];
    const float* scale = (const float*)d_in[2];
    const float* bias  = (const float*)d_in[3];
    float* y = (float*)d_out;

    float*    stats = (float*)((char*)d_ws + STATS_OFF);
    _Float16* Kf    = (_Float16*)((char*)d_ws + KF_OFF);

    convert_k_kernel<<<108, 256, 0, stream>>>(K, Kf, stats);
    conv_mfma_kernel<<<N_ * 13 * 7, 256, 0, stream>>>(x, Kf, y, stats);
    const int total4 = N_ * DOUT * DOUT * DOUT * (COUT / 4);
    gn_apply_kernel<<<(total4 + 255) / 256, 256, 0, stream>>>(y, stats, scale, bias);
}